// Round 1
// baseline (481.555 us; speedup 1.0000x reference)
//
#include <hip/hip_runtime.h>
#include <stdint.h>

// y[row, 64k+m] = (1/48) * sum_j H36[k][j] * sum_l (-1)^popcount(m&l) * x[row, 64j+l]
// Row = 2304 = 36 blocks x 64. One wave (64 lanes) handles 2 rows:
//   lane bit5 = row-sub, q = lane&31 owns columns {2q, 2q+1} (float2) for all 36 j.
// FWHT64: bit0 within-lane, bits1..5 via shfl_xor masks 1,2,4,8,16.
// H36 matmul: y[k] = S - 2*N[k] with N[k] = sum over negative entries (compile-time masks).

constexpr uint64_t neg_mask(const char* s) {
    uint64_t m = 0;
    for (int j = 0; j < 36; ++j)
        if (s[j] == '-') m |= (1ull << j);
    return m;
}

constexpr uint64_t NEG[36] = {
    neg_mask("++++++++++++++++++-+++++++++++++++++"),
    neg_mask("++++-+---++---+-+++-++-+---++---+-++"),
    neg_mask("+++++-+---++---+-+++-++-+---++---+-+"),
    neg_mask("++++++-+---++---+-+++-++-+---++---+-"),
    neg_mask("+-+++++-+---++---++-++-++-+---++---+"),
    neg_mask("++-+++++-+---++---++-++-++-+---++---"),
    neg_mask("+-+-+++++-+---++--+-+-++-++-+---++--"),
    neg_mask("+--+-+++++-+---++-+--+-++-++-+---++-"),
    neg_mask("+---+-+++++-+---+++---+-++-++-+---++"),
    neg_mask("++---+-+++++-+---+++---+-++-++-+---+"),
    neg_mask("+++---+-+++++-+---+++---+-++-++-+---"),
    neg_mask("+-++---+-+++++-+--+-++---+-++-++-+--"),
    neg_mask("+--++---+-+++++-+-+--++---+-++-++-+-"),
    neg_mask("+---++---+-+++++-++---++---+-++-++-+"),
    neg_mask("++---++---+-+++++-++---++---+-++-++-"),
    neg_mask("+-+---++---+-++++++-+---++---+-++-++"),
    neg_mask("++-+---++---+-++++++-+---++---+-++-+"),
    neg_mask("+++-+---++---+-++++++-+---++---+-++-"),
    neg_mask("-+++++++++++++++++------------------"),
    neg_mask("+-++-+---++---+-++----+-+++--+++-+--"),
    neg_mask("++-++-+---++---+-+-----+-+++--+++-+-"),
    neg_mask("+++-++-+---++---+-------+-+++--+++-+"),
    neg_mask("+-++-++-+---++---+-+-----+-+++--+++-"),
    neg_mask("++-++-++-+---++-----+-----+-+++--+++"),
    neg_mask("+-+-++-++-+---++---+-+-----+-+++--++"),
    neg_mask("+--+-++-++-+---++--++-+-----+-+++--+"),
    neg_mask("+---+-++-++-+---++-+++-+-----+-+++--"),
    neg_mask("++---+-++-++-+---+--+++-+-----+-+++-"),
    neg_mask("+++---+-++-++-+------+++-+-----+-+++"),
    neg_mask("+-++---+-++-++-+---+--+++-+-----+-++"),
    neg_mask("+--++---+-++-++-+--++--+++-+-----+-+"),
    neg_mask("+---++---+-++-++-+-+++--+++-+-----+-"),
    neg_mask("++---++---+-++-++---+++--+++-+-----+"),
    neg_mask("+-+---++---+-++-++-+-+++--+++-+-----"),
    neg_mask("++-+---++---+-++-+--+-+++--+++-+----"),
    neg_mask("+++-+---++---+-++----+-+++--+++-+---"),
};

#define ROWLEN 2304

__global__ __launch_bounds__(256) void had_kernel(const float* __restrict__ x,
                                                  float* __restrict__ out,
                                                  int n_rows) {
    const int tid  = threadIdx.x;
    const int wave = tid >> 6;
    const int lane = tid & 63;
    const int q    = lane & 31;   // column pair index within row
    const int rsub = lane >> 5;   // which of the 2 rows this wave handles

    const long long row = (long long)blockIdx.x * 8 + wave * 2 + rsub;
    if (row >= n_rows) return;

    const float* xr = x + row * ROWLEN + 2 * q;

    float v0[36], v1[36];
#pragma unroll
    for (int j = 0; j < 36; ++j) {
        float2 t = *(const float2*)(xr + j * 64);
        v0[j] = t.x;
        v1[j] = t.y;
    }

    // FWHT stage for l-bit 0 (within lane): slot0 = sum, slot1 = diff
#pragma unroll
    for (int j = 0; j < 36; ++j) {
        float a = v0[j], b = v1[j];
        v0[j] = a + b;
        v1[j] = a - b;
    }

    // FWHT stages for l-bits 1..5: xor-shuffle on lane bits 0..4
#pragma unroll
    for (int p = 0; p < 5; ++p) {
        const int mask = 1 << p;
        const float s = (q & mask) ? -1.0f : 1.0f;  // bit set: partner - v ; else v + partner
#pragma unroll
        for (int j = 0; j < 36; ++j) {
            float p0 = __shfl_xor(v0[j], mask, 64);
            float p1 = __shfl_xor(v1[j], mask, 64);
            v0[j] = fmaf(v0[j], s, p0);
            v1[j] = fmaf(v1[j], s, p1);
        }
    }

    // Full sums over j
    float S0 = 0.0f, S1 = 0.0f;
#pragma unroll
    for (int j = 0; j < 36; ++j) {
        S0 += v0[j];
        S1 += v1[j];
    }
    const float inv48 = 1.0f / 48.0f;
    const float m2_48 = -2.0f / 48.0f;
    S0 *= inv48;
    S1 *= inv48;

    float* yr = out + row * ROWLEN + 2 * q;

    // y[k] = S/48 - (2/48) * N[k], N[k] = sum of v[j] over negative H36 entries.
    // NEG[k] is constexpr; full unroll folds the bit tests into straight adds.
#pragma unroll
    for (int k = 0; k < 36; ++k) {
        const uint64_t m = NEG[k];
        float n0 = 0.0f, n1 = 0.0f;
#pragma unroll
        for (int j = 0; j < 36; ++j) {
            if ((m >> j) & 1) {
                n0 += v0[j];
                n1 += v1[j];
            }
        }
        float y0 = fmaf(n0, m2_48, S0);
        float y1 = fmaf(n1, m2_48, S1);
        *(float2*)(yr + k * 64) = make_float2(y0, y1);
    }
}

extern "C" void kernel_launch(void* const* d_in, const int* in_sizes, int n_in,
                              void* d_out, int out_size, void* d_ws, size_t ws_size,
                              hipStream_t stream) {
    const float* x = (const float*)d_in[0];
    float* out = (float*)d_out;
    const int n_rows = in_sizes[0] / ROWLEN;          // 32768
    const int rows_per_block = 8;                     // 4 waves x 2 rows
    const int grid = (n_rows + rows_per_block - 1) / rows_per_block;
    hipLaunchKernelGGL(had_kernel, dim3(grid), dim3(256), 0, stream, x, out, n_rows);
}